// Round 1
// baseline (189.899 us; speedup 1.0000x reference)
//
#include <hip/hip_runtime.h>
#include <hip/hip_bf16.h>

// MoLoRA = base linear + top-2 routed LoRA.
// Restructured as:
//   Abuf[T,2176] = [ bf16(x) | bf16(alpha*cw*(x@A2^T)) ]      (A2 = A_w as [128,2048])
//   Bfull[O,2176] = [ bf16(W) | bf16(B2^T) ]   (B2[e*16+r,o]=B_w[e,o,r])
//   out[T,O] = Abuf @ Bfull^T     -- single bf16 MFMA GEMM, K=2176
// Sizes fixed: T=4096, H=2048, O=2048, E=8, R=16, Kaug=2176.

typedef __bf16 bf16x8 __attribute__((ext_vector_type(8)));
typedef float f32x4 __attribute__((ext_vector_type(4)));

__device__ __forceinline__ __bf16 f2bf(float f) {
  union { float f; unsigned u; } v; v.f = f;
  unsigned r = (v.u + 0x7FFFu + ((v.u >> 16) & 1u)) >> 16;  // RNE
  unsigned short s = (unsigned short)r;
  return __builtin_bit_cast(__bf16, s);
}

__device__ __forceinline__ void ld_lds16(const void* g, void* l) {
  // async global->LDS, 16B per lane; LDS dest = wave-uniform base + lane*16
  __builtin_amdgcn_global_load_lds((__attribute__((address_space(1))) void*)g,
                                   (__attribute__((address_space(3))) void*)l,
                                   16, 0, 0);
}

// ---------------- fp32 -> bf16 row converter (2048-wide rows) ----------------
// grid = rows, block = 256; each thread converts 8 contiguous elems.
__global__ void conv2048(const float* __restrict__ src, __bf16* __restrict__ dst,
                         int dld) {
  const size_t r = blockIdx.x;
  const int c = threadIdx.x * 8;
  const float4* s = (const float4*)(src + r * 2048 + c);
  float4 a = s[0], b = s[1];
  bf16x8 v;
  v[0] = f2bf(a.x); v[1] = f2bf(a.y); v[2] = f2bf(a.z); v[3] = f2bf(a.w);
  v[4] = f2bf(b.x); v[5] = f2bf(b.y); v[6] = f2bf(b.z); v[7] = f2bf(b.w);
  *(bf16x8*)(dst + r * dld + c) = v;
}

// ---------------- pack B_w [E,O,R] -> Bfull[:, 2048 + e*16 + r] ----------------
// one thread per (e,o): reads 16 contiguous floats, writes 16 bf16.
__global__ void pack_bw(const float* __restrict__ Bw, __bf16* __restrict__ Bfull) {
  const int idx = blockIdx.x * 256 + threadIdx.x;  // 0..16383
  const int e = idx >> 11, o = idx & 2047;
  const float4* s = (const float4*)(Bw + ((size_t)e * 2048 + o) * 16);
  float4 v0 = s[0], v1 = s[1], v2 = s[2], v3 = s[3];
  __bf16* d = Bfull + (size_t)o * 2176 + 2048 + e * 16;
  bf16x8 lo, hi;
  lo[0] = f2bf(v0.x); lo[1] = f2bf(v0.y); lo[2] = f2bf(v0.z); lo[3] = f2bf(v0.w);
  lo[4] = f2bf(v1.x); lo[5] = f2bf(v1.y); lo[6] = f2bf(v1.z); lo[7] = f2bf(v1.w);
  hi[0] = f2bf(v2.x); hi[1] = f2bf(v2.y); hi[2] = f2bf(v2.z); hi[3] = f2bf(v2.w);
  hi[4] = f2bf(v3.x); hi[5] = f2bf(v3.y); hi[6] = f2bf(v3.z); hi[7] = f2bf(v3.w);
  *(bf16x8*)d = lo;
  *(bf16x8*)(d + 8) = hi;
}

// ---------------- router + x->bf16 conversion ----------------
// grid = 4096 (one block per token), block = 256.
__global__ void router_kernel(const float* __restrict__ x, const float* __restrict__ gw,
                              __bf16* __restrict__ Abuf, float* __restrict__ cw) {
  const int t = blockIdx.x, tid = threadIdx.x;
  const float* xr = x + (size_t)t * 2048;
  const int c = tid * 8;
  float4 v0 = *(const float4*)(xr + c);
  float4 v1 = *(const float4*)(xr + c + 4);
  float xs[8] = {v0.x, v0.y, v0.z, v0.w, v1.x, v1.y, v1.z, v1.w};
  bf16x8 bv;
#pragma unroll
  for (int j = 0; j < 8; ++j) bv[j] = f2bf(xs[j]);
  *(bf16x8*)(Abuf + (size_t)t * 2176 + c) = bv;

  float acc[8] = {0, 0, 0, 0, 0, 0, 0, 0};
#pragma unroll
  for (int j = 0; j < 8; ++j) {
    const float xv = xs[j];
#pragma unroll
    for (int e = 0; e < 8; ++e) acc[e] += xv * gw[e * 2048 + c + j];
  }
#pragma unroll
  for (int e = 0; e < 8; ++e)
    for (int off = 32; off; off >>= 1) acc[e] += __shfl_down(acc[e], off);

  __shared__ float red[4][8];
  const int wave = tid >> 6, lane = tid & 63;
  if (lane == 0) {
#pragma unroll
    for (int e = 0; e < 8; ++e) red[wave][e] = acc[e];
  }
  __syncthreads();
  if (tid == 0) {
    float lg[8];
#pragma unroll
    for (int e = 0; e < 8; ++e) lg[e] = red[0][e] + red[1][e] + red[2][e] + red[3][e];
    int a = 0;
    for (int e = 1; e < 8; ++e) if (lg[e] > lg[a]) a = e;
    int b = (a == 0) ? 1 : 0;
    for (int e = 0; e < 8; ++e) if (e != a && lg[e] > lg[b]) b = e;
    // softmax + top2 + renorm collapses to 2-way softmax on the top-2 logits
    const float d = __expf(lg[b] - lg[a]);
    const float wa = 1.0f / (1.0f + d), wb = d / (1.0f + d);
    float o[8] = {0, 0, 0, 0, 0, 0, 0, 0};
    o[a] = wa; o[b] = wb;
#pragma unroll
    for (int e = 0; e < 8; ++e) cw[t * 8 + e] = o[e];
  }
}

// ---------------- t2 reduce + scale + bf16 into Abuf[:, 2048:2176] ----------------
__global__ void t2_finish(const float* __restrict__ tpart, const float* __restrict__ cw,
                          __bf16* __restrict__ Abuf) {
  const int idx = blockIdx.x * 256 + threadIdx.x;  // 0..524287
  const int t = idx >> 7, k2 = idx & 127;
  float s = tpart[idx] + tpart[idx + 524288] + tpart[idx + 2 * 524288] +
            tpart[idx + 3 * 524288];
  const float w = cw[t * 8 + (k2 >> 4)] * 16.0f;  // LORA_ALPHA folded here
  Abuf[(size_t)t * 2176 + 2048 + k2] = f2bf(s * w);
}

// ---------------- MFMA GEMM: C[m,n] = sum_k A[m,k]*B[n,k] (both K-major) ----------------
// 128x128 tile, BK=64, 256 threads (4 waves, each 64x64 = 4x4 MFMA 16x16x32 tiles).
// blockIdx.z = split-K part: k range [z*kiters*64, ...), C += z*czstride.
__global__ __launch_bounds__(256) void mfma_gemm_bt(
    const __bf16* __restrict__ A, const __bf16* __restrict__ B,
    float* __restrict__ C, int lda, int ldb, int ldc, int kiters,
    long long czstride) {
  __shared__ __align__(16) __bf16 As[128 * 64];
  __shared__ __align__(16) __bf16 Bs[128 * 64];
  const int tid = threadIdx.x;
  const int wave = tid >> 6;
  const int lane = tid & 63;
  const int tm = blockIdx.x * 128;
  const int tn = blockIdx.y * 128;
  C += (long long)blockIdx.z * czstride;

  const int wm = (wave >> 1) * 64;
  const int wn = (wave & 1) * 64;
  const int srow = lane >> 3;        // row within an 8-row staging chunk
  const int skoff = (lane & 7) * 8;  // k-offset (elements) within chunk

  f32x4 acc[4][4] = {};

  int kcur = blockIdx.z * kiters * 64;
  for (int kt = 0; kt < kiters; ++kt) {
#pragma unroll
    for (int r = 0; r < 4; ++r) {
      const int ch = r * 4 + wave;  // 16 chunks of 8 rows each
      ld_lds16(A + (size_t)(tm + ch * 8 + srow) * lda + kcur + skoff, &As[ch * 512]);
      ld_lds16(B + (size_t)(tn + ch * 8 + srow) * ldb + kcur + skoff, &Bs[ch * 512]);
    }
    __syncthreads();  // drains vmcnt for the global_load_lds
#pragma unroll
    for (int ks = 0; ks < 2; ++ks) {
      bf16x8 af[4], bfg[4];
#pragma unroll
      for (int i = 0; i < 4; ++i)
        af[i] = *(const bf16x8*)&As[(wm + i * 16 + (lane & 15)) * 64 + ks * 32 + (lane >> 4) * 8];
#pragma unroll
      for (int j = 0; j < 4; ++j)
        bfg[j] = *(const bf16x8*)&Bs[(wn + j * 16 + (lane & 15)) * 64 + ks * 32 + (lane >> 4) * 8];
#pragma unroll
      for (int i = 0; i < 4; ++i)
#pragma unroll
        for (int j = 0; j < 4; ++j)
          acc[i][j] = __builtin_amdgcn_mfma_f32_16x16x32_bf16(af[i], bfg[j], acc[i][j], 0, 0, 0);
    }
    __syncthreads();
    kcur += 64;
  }

  // C/D layout: col = lane&15, row = (lane>>4)*4 + reg
  const int crow0 = tm + wm + (lane >> 4) * 4;
  const int ccol0 = tn + wn + (lane & 15);
#pragma unroll
  for (int i = 0; i < 4; ++i)
#pragma unroll
    for (int j = 0; j < 4; ++j)
#pragma unroll
      for (int rg = 0; rg < 4; ++rg)
        C[(size_t)(crow0 + i * 16 + rg) * ldc + ccol0 + j * 16] = acc[i][j][rg];
}

extern "C" void kernel_launch(void* const* d_in, const int* in_sizes, int n_in,
                              void* d_out, int out_size, void* d_ws, size_t ws_size,
                              hipStream_t stream) {
  const float* x = (const float*)d_in[0];       // [2,2048,2048] -> [4096,2048]
  const float* weight = (const float*)d_in[1];  // [2048,2048]
  const float* gate_w = (const float*)d_in[2];  // [8,2048]
  const float* A_w = (const float*)d_in[3];     // [8,16,2048] == [128,2048]
  const float* B_w = (const float*)d_in[4];     // [8,2048,16]
  float* out = (float*)d_out;                   // [4096,2048]

  char* ws = (char*)d_ws;
  __bf16* Abuf = (__bf16*)ws;                 // [4096,2176] bf16 = 17,825,792 B
  __bf16* Bfull = (__bf16*)(ws + 17825792);   // [2048,2176] bf16 =  8,912,896 B
  __bf16* A2 = (__bf16*)(ws + 26738688);      // [128,2048]  bf16 =    524,288 B
  float* tpart = (float*)(ws + 27262976);     // [4,4096,128] f32 =  8,388,608 B
  float* cw = (float*)(ws + 35651584);        // [4096,8]     f32 =    131,072 B

  // 1. W -> bf16 into Bfull[:, 0:2048]
  conv2048<<<2048, 256, 0, stream>>>(weight, Bfull, 2176);
  // 2. A_w -> bf16 A2 (contiguous reshape)
  conv2048<<<128, 256, 0, stream>>>(A_w, A2, 2048);
  // 3. B_w transpose-pack into Bfull[:, 2048:2176]
  pack_bw<<<64, 256, 0, stream>>>(B_w, Bfull);
  // 4. router (fp32 logits/softmax/top2) + x -> bf16 into Abuf[:, 0:2048]
  router_kernel<<<4096, 256, 0, stream>>>(x, gate_w, Abuf, cw);
  // 5. t_part[z] = x @ A2^T  (split-K=4, 128 blocks)
  mfma_gemm_bt<<<dim3(32, 1, 4), 256, 0, stream>>>(Abuf, A2, tpart, 2176, 2048, 128,
                                                   8, 524288LL);
  // 6. t2 = alpha*cw*sum_z t_part -> bf16 into Abuf[:, 2048:2176]
  t2_finish<<<2048, 256, 0, stream>>>(tpart, cw, Abuf);
  // 7. out = Abuf @ Bfull^T  (K=2176 fuses base + LoRA-up)
  mfma_gemm_bt<<<dim3(32, 16, 1), 256, 0, stream>>>(Abuf, Bfull, out, 2176, 2176,
                                                    2048, 34, 0LL);
}

// Round 2
// 174.483 us; speedup vs baseline: 1.0884x; 1.0884x over previous
//
#include <hip/hip_runtime.h>
#include <hip/hip_bf16.h>

// MoLoRA = base linear + top-2 routed LoRA.
//   Abuf[T,2176] = [ bf16(x) | bf16(alpha*cw*(x@A2^T)) ]      (A2 = A_w as [128,2048])
//   Bfull[O,2176] = [ bf16(W) | bf16(B2^T) ]   (B2[e*16+r,o]=B_w[e,o,r])
//   out[T,O] = Abuf @ Bfull^T     -- single bf16 MFMA GEMM, K=2176
// T=4096, H=2048, O=2048, E=8, R=16, Kaug=2176.
//
// R1: LDS staged via global_load_lds with XOR k-chunk swizzle (lane l stages
// k-chunk (l&7)^(l>>3)); fragment reads XOR back -> all 8 bank groups active,
// b128 reads at the 8-clock floor (was: 16-way conflict, 2x LDS time).

typedef __bf16 bf16x8 __attribute__((ext_vector_type(8)));
typedef float f32x4 __attribute__((ext_vector_type(4)));

__device__ __forceinline__ __bf16 f2bf(float f) {
  union { float f; unsigned u; } v; v.f = f;
  unsigned r = (v.u + 0x7FFFu + ((v.u >> 16) & 1u)) >> 16;  // RNE
  unsigned short s = (unsigned short)r;
  return __builtin_bit_cast(__bf16, s);
}

__device__ __forceinline__ void ld_lds16(const void* g, void* l) {
  __builtin_amdgcn_global_load_lds((__attribute__((address_space(1))) void*)g,
                                   (__attribute__((address_space(3))) void*)l,
                                   16, 0, 0);
}

// ---------------- fused prep: W->Bfull[:,0:2048], A_w->A2, B_w->Bfull[:,2048:] ----
__global__ void prep_kernel(const float* __restrict__ W, const float* __restrict__ Aw,
                            const float* __restrict__ Bw, __bf16* __restrict__ Bfull,
                            __bf16* __restrict__ A2) {
  const int b = blockIdx.x, tid = threadIdx.x;
  if (b < 2176) {
    // row conversion: rows 0..2047 = W -> Bfull (ld 2176); 2048..2175 = Aw -> A2 (ld 2048)
    const float* src = (b < 2048) ? (W + (size_t)b * 2048)
                                  : (Aw + (size_t)(b - 2048) * 2048);
    __bf16* dst = (b < 2048) ? (Bfull + (size_t)b * 2176)
                             : (A2 + (size_t)(b - 2048) * 2048);
    const int c = tid * 8;
    float4 a = *(const float4*)(src + c);
    float4 d = *(const float4*)(src + c + 4);
    bf16x8 v;
    v[0] = f2bf(a.x); v[1] = f2bf(a.y); v[2] = f2bf(a.z); v[3] = f2bf(a.w);
    v[4] = f2bf(d.x); v[5] = f2bf(d.y); v[6] = f2bf(d.z); v[7] = f2bf(d.w);
    *(bf16x8*)(dst + c) = v;
  } else {
    // pack B_w [E,O,R] -> Bfull[o, 2048 + e*16 + r]
    const int idx = (b - 2176) * 256 + tid;  // 0..16383
    const int e = idx >> 11, o = idx & 2047;
    const float4* s = (const float4*)(Bw + ((size_t)e * 2048 + o) * 16);
    float4 v0 = s[0], v1 = s[1], v2 = s[2], v3 = s[3];
    __bf16* d = Bfull + (size_t)o * 2176 + 2048 + e * 16;
    bf16x8 lo, hi;
    lo[0] = f2bf(v0.x); lo[1] = f2bf(v0.y); lo[2] = f2bf(v0.z); lo[3] = f2bf(v0.w);
    lo[4] = f2bf(v1.x); lo[5] = f2bf(v1.y); lo[6] = f2bf(v1.z); lo[7] = f2bf(v1.w);
    hi[0] = f2bf(v2.x); hi[1] = f2bf(v2.y); hi[2] = f2bf(v2.z); hi[3] = f2bf(v2.w);
    hi[4] = f2bf(v3.x); hi[5] = f2bf(v3.y); hi[6] = f2bf(v3.z); hi[7] = f2bf(v3.w);
    *(bf16x8*)d = lo;
    *(bf16x8*)(d + 8) = hi;
  }
}

// ---------------- router (8 tokens/block, gw in LDS) + x->bf16 --------------
__global__ __launch_bounds__(256) void router_kernel(
    const float* __restrict__ x, const float* __restrict__ gw,
    __bf16* __restrict__ Abuf, float* __restrict__ cw) {
  __shared__ float gws[8 * 2048];          // 64 KB
  __shared__ float red[8][4][8];           // [token][wave][expert]
  const int tid = threadIdx.x;
  const int wave = tid >> 6, lane = tid & 63;
  // stage gw coalesced: 16384 floats = 4096 float4 / 256 threads
  for (int i = tid; i < 4096; i += 256) ((float4*)gws)[i] = ((const float4*)gw)[i];
  __syncthreads();

  const int t0 = blockIdx.x * 8;
  const int c = tid * 8;
  for (int tk = 0; tk < 8; ++tk) {
    const int t = t0 + tk;
    const float* xr = x + (size_t)t * 2048;
    float4 v0 = *(const float4*)(xr + c);
    float4 v1 = *(const float4*)(xr + c + 4);
    float xs[8] = {v0.x, v0.y, v0.z, v0.w, v1.x, v1.y, v1.z, v1.w};
    bf16x8 bv;
#pragma unroll
    for (int j = 0; j < 8; ++j) bv[j] = f2bf(xs[j]);
    *(bf16x8*)(Abuf + (size_t)t * 2176 + c) = bv;

    float acc[8] = {0, 0, 0, 0, 0, 0, 0, 0};
#pragma unroll
    for (int j = 0; j < 8; ++j) {
      const float xv = xs[j];
#pragma unroll
      for (int e = 0; e < 8; ++e) acc[e] += xv * gws[e * 2048 + c + j];
    }
#pragma unroll
    for (int e = 0; e < 8; ++e)
      for (int off = 32; off; off >>= 1) acc[e] += __shfl_down(acc[e], off);
    if (lane == 0) {
#pragma unroll
      for (int e = 0; e < 8; ++e) red[tk][wave][e] = acc[e];
    }
  }
  __syncthreads();
  if (tid < 8) {
    const int tk = tid, t = t0 + tk;
    float lg[8];
#pragma unroll
    for (int e = 0; e < 8; ++e)
      lg[e] = red[tk][0][e] + red[tk][1][e] + red[tk][2][e] + red[tk][3][e];
    int a = 0;
    for (int e = 1; e < 8; ++e) if (lg[e] > lg[a]) a = e;
    int b = (a == 0) ? 1 : 0;
    for (int e = 0; e < 8; ++e) if (e != a && lg[e] > lg[b]) b = e;
    const float d = __expf(lg[b] - lg[a]);
    const float wa = 1.0f / (1.0f + d), wb = d / (1.0f + d);
    float o[8] = {0, 0, 0, 0, 0, 0, 0, 0};
    o[a] = wa; o[b] = wb;
#pragma unroll
    for (int e = 0; e < 8; ++e) cw[t * 8 + e] = o[e];
  }
}

// ---------------- t2 reduce + scale + bf16 into Abuf[:, 2048:2176] ----------------
__global__ void t2_finish(const float* __restrict__ tpart, const float* __restrict__ cw,
                          __bf16* __restrict__ Abuf) {
  const int idx = blockIdx.x * 256 + threadIdx.x;  // 0..524287
  const int t = idx >> 7, k2 = idx & 127;
  float s = tpart[idx] + tpart[idx + 524288] + tpart[idx + 2 * 524288] +
            tpart[idx + 3 * 524288];
  const float w = cw[t * 8 + (k2 >> 4)] * 16.0f;  // LORA_ALPHA folded here
  Abuf[(size_t)t * 2176 + 2048 + k2] = f2bf(s * w);
}

// ---------------- MFMA GEMM: C[m,n] = sum_k A[m,k]*B[n,k] (both K-major) ----------------
// 128x128 tile, BK=64, 256 threads (4 waves, each 64x64 = 4x4 MFMA 16x16x32 tiles).
// LDS layout (per matrix): 16 chunks of 8 rows; element (r,k) lives at
//   (r>>3)*512 + (r&7)*64 + (((k>>3) ^ (r&7)) * 8) + (k&7)      [elements]
// achieved by staging lane l -> global k-chunk (l&7)^(l>>3) of row l>>3.
__global__ __launch_bounds__(256) void mfma_gemm_bt(
    const __bf16* __restrict__ A, const __bf16* __restrict__ B,
    float* __restrict__ C, int lda, int ldb, int ldc, int kiters,
    long long czstride) {
  __shared__ __align__(16) __bf16 As[128 * 64];
  __shared__ __align__(16) __bf16 Bs[128 * 64];
  const int tid = threadIdx.x;
  const int wave = tid >> 6;
  const int lane = tid & 63;
  const int tm = blockIdx.x * 128;
  const int tn = blockIdx.y * 128;
  C += (long long)blockIdx.z * czstride;

  const int wm = (wave >> 1) * 64;
  const int wn = (wave & 1) * 64;
  const int srow = lane >> 3;                        // 0..7: row within 8-row chunk
  const int skoff = ((lane & 7) ^ srow) * 8;         // XOR-swizzled k offset (elems)

  const int rlo = lane & 7;                          // row&7 at fragment read
  const int rb3 = (lane >> 3) & 1;                   // bit3 of row
  const int qb = lane >> 4;                          // 0..3

  f32x4 acc[4][4] = {};

  int kcur = blockIdx.z * kiters * 64;
  for (int kt = 0; kt < kiters; ++kt) {
#pragma unroll
    for (int r = 0; r < 4; ++r) {
      const int ch = r * 4 + wave;  // 16 chunks of 8 rows each
      ld_lds16(A + (size_t)(tm + ch * 8 + srow) * lda + kcur + skoff, &As[ch * 512]);
      ld_lds16(B + (size_t)(tn + ch * 8 + srow) * ldb + kcur + skoff, &Bs[ch * 512]);
    }
    __syncthreads();  // drains vmcnt for the global_load_lds
#pragma unroll
    for (int ks = 0; ks < 2; ++ks) {
      bf16x8 af[4], bfg[4];
#pragma unroll
      for (int i = 0; i < 4; ++i) {
        const int rh = ((wm + i * 16) >> 3) + rb3;
        const int q = (ks * 4 + qb) ^ rlo;
        af[i] = *(const bf16x8*)&As[rh * 512 + rlo * 64 + q * 8];
      }
#pragma unroll
      for (int j = 0; j < 4; ++j) {
        const int rh = ((wn + j * 16) >> 3) + rb3;
        const int q = (ks * 4 + qb) ^ rlo;
        bfg[j] = *(const bf16x8*)&Bs[rh * 512 + rlo * 64 + q * 8];
      }
#pragma unroll
      for (int i = 0; i < 4; ++i)
#pragma unroll
        for (int j = 0; j < 4; ++j)
          acc[i][j] = __builtin_amdgcn_mfma_f32_16x16x32_bf16(af[i], bfg[j], acc[i][j], 0, 0, 0);
    }
    __syncthreads();
    kcur += 64;
  }

  // C/D layout: col = lane&15, row = (lane>>4)*4 + reg
  const int crow0 = tm + wm + (lane >> 4) * 4;
  const int ccol0 = tn + wn + (lane & 15);
#pragma unroll
  for (int i = 0; i < 4; ++i)
#pragma unroll
    for (int j = 0; j < 4; ++j)
#pragma unroll
      for (int rg = 0; rg < 4; ++rg)
        C[(size_t)(crow0 + i * 16 + rg) * ldc + ccol0 + j * 16] = acc[i][j][rg];
}

extern "C" void kernel_launch(void* const* d_in, const int* in_sizes, int n_in,
                              void* d_out, int out_size, void* d_ws, size_t ws_size,
                              hipStream_t stream) {
  const float* x = (const float*)d_in[0];       // [2,2048,2048] -> [4096,2048]
  const float* weight = (const float*)d_in[1];  // [2048,2048]
  const float* gate_w = (const float*)d_in[2];  // [8,2048]
  const float* A_w = (const float*)d_in[3];     // [8,16,2048] == [128,2048]
  const float* B_w = (const float*)d_in[4];     // [8,2048,16]
  float* out = (float*)d_out;                   // [4096,2048]

  char* ws = (char*)d_ws;
  __bf16* Abuf = (__bf16*)ws;                 // [4096,2176] bf16 = 17,825,792 B
  __bf16* Bfull = (__bf16*)(ws + 17825792);   // [2048,2176] bf16 =  8,912,896 B
  __bf16* A2 = (__bf16*)(ws + 26738688);      // [128,2048]  bf16 =    524,288 B
  float* tpart = (float*)(ws + 27262976);     // [4,4096,128] f32 =  8,388,608 B
  float* cw = (float*)(ws + 35651584);        // [4096,8]     f32 =    131,072 B

  // 1. prep: W -> Bfull[:,0:2048]; A_w -> A2; B_w -> Bfull[:,2048:2176]
  prep_kernel<<<2240, 256, 0, stream>>>(weight, A_w, B_w, Bfull, A2);
  // 2. router (fp32) + x -> bf16 into Abuf[:, 0:2048]
  router_kernel<<<512, 256, 0, stream>>>(x, gate_w, Abuf, cw);
  // 3. t_part[z] = x @ A2^T  (split-K=4, 128 blocks)
  mfma_gemm_bt<<<dim3(32, 1, 4), 256, 0, stream>>>(Abuf, A2, tpart, 2176, 2048, 128,
                                                   8, 524288LL);
  // 4. t2 = alpha*cw*sum_z t_part -> bf16 into Abuf[:, 2048:2176]
  t2_finish<<<2048, 256, 0, stream>>>(tpart, cw, Abuf);
  // 5. out = Abuf @ Bfull^T  (K=2176 fuses base + LoRA-up)
  mfma_gemm_bt<<<dim3(32, 16, 1), 256, 0, stream>>>(Abuf, Bfull, out, 2176, 2176,
                                                    2048, 34, 0LL);
}

// Round 3
// 166.492 us; speedup vs baseline: 1.1406x; 1.0480x over previous
//
#include <hip/hip_runtime.h>
#include <hip/hip_bf16.h>

// MoLoRA = base linear + top-2 routed LoRA.
//   Abuf[T,2176] = [ bf16(x) | bf16(alpha*cw*(x@A2^T)) ]      (A2 = A_w as [128,2048])
//   Bfull[O,2176] = [ bf16(W) | bf16(B2^T) ]   (B2[e*16+r,o]=B_w[e,o,r])
//   out[T,O] = Abuf @ Bfull^T     -- single bf16 MFMA GEMM, K=2176
// T=4096, H=2048, O=2048, E=8, R=16, Kaug=2176.
//
// R1: XOR k-chunk LDS swizzle -> SQ_LDS_BANK_CONFLICT 1.34e7 -> 0.
// R2: (a) main GEMM 128x64 tiles, 2-wave blocks, grid 1024 = 4 blocks/CU
//     (was 512 = 2/CU, occupancy-limited); (b) router+t2gemm+t2finish fused
//     into one kernel (3 dispatches total, no tpart round-trip).

typedef __bf16 bf16x8 __attribute__((ext_vector_type(8)));
typedef float f32x4 __attribute__((ext_vector_type(4)));

__device__ __forceinline__ __bf16 f2bf(float f) {
  union { float f; unsigned u; } v; v.f = f;
  unsigned r = (v.u + 0x7FFFu + ((v.u >> 16) & 1u)) >> 16;  // RNE
  unsigned short s = (unsigned short)r;
  return __builtin_bit_cast(__bf16, s);
}

__device__ __forceinline__ void ld_lds16(const void* g, void* l) {
  __builtin_amdgcn_global_load_lds((__attribute__((address_space(1))) void*)g,
                                   (__attribute__((address_space(3))) void*)l,
                                   16, 0, 0);
}

// ---------------- fused prep: W->Bfull[:,0:2048], A_w->A2, B_w->Bfull[:,2048:] ----
__global__ void prep_kernel(const float* __restrict__ W, const float* __restrict__ Aw,
                            const float* __restrict__ Bw, __bf16* __restrict__ Bfull,
                            __bf16* __restrict__ A2) {
  const int b = blockIdx.x, tid = threadIdx.x;
  if (b < 2176) {
    const float* src = (b < 2048) ? (W + (size_t)b * 2048)
                                  : (Aw + (size_t)(b - 2048) * 2048);
    __bf16* dst = (b < 2048) ? (Bfull + (size_t)b * 2176)
                             : (A2 + (size_t)(b - 2048) * 2048);
    const int c = tid * 8;
    float4 a = *(const float4*)(src + c);
    float4 d = *(const float4*)(src + c + 4);
    bf16x8 v;
    v[0] = f2bf(a.x); v[1] = f2bf(a.y); v[2] = f2bf(a.z); v[3] = f2bf(a.w);
    v[4] = f2bf(d.x); v[5] = f2bf(d.y); v[6] = f2bf(d.z); v[7] = f2bf(d.w);
    *(bf16x8*)(dst + c) = v;
  } else {
    // pack B_w [E,O,R] -> Bfull[o, 2048 + e*16 + r]
    const int idx = (b - 2176) * 256 + tid;  // 0..16383
    const int e = idx >> 11, o = idx & 2047;
    const float4* s = (const float4*)(Bw + ((size_t)e * 2048 + o) * 16);
    float4 v0 = s[0], v1 = s[1], v2 = s[2], v3 = s[3];
    __bf16* d = Bfull + (size_t)o * 2176 + 2048 + e * 16;
    bf16x8 lo, hi;
    lo[0] = f2bf(v0.x); lo[1] = f2bf(v0.y); lo[2] = f2bf(v0.z); lo[3] = f2bf(v0.w);
    lo[4] = f2bf(v1.x); lo[5] = f2bf(v1.y); lo[6] = f2bf(v1.z); lo[7] = f2bf(v1.w);
    hi[0] = f2bf(v2.x); hi[1] = f2bf(v2.y); hi[2] = f2bf(v2.z); hi[3] = f2bf(v2.w);
    hi[4] = f2bf(v3.x); hi[5] = f2bf(v3.y); hi[6] = f2bf(v3.z); hi[7] = f2bf(v3.w);
    *(bf16x8*)d = lo;
    *(bf16x8*)(d + 8) = hi;
  }
}

// ---------------- fused router + LoRA-down (t2) ----------------
// 16 tokens/block, grid 256. Phases:
//  1. x -> bf16 -> Abuf[:,0:2048] + LDS xs (row pad +8 breaks bank aliasing)
//  2. fp32 logits (token=lane&15, slice=tid>>4), shuffle+LDS reduce, top-2 -> cws
//  3. t[16,128] = xs @ A2^T via MFMA (B-frags straight from L2-hot A2)
//  4. scale 16*cw, bf16, scatter into Abuf[:,2048:2176]
__global__ __launch_bounds__(256) void router_t2(
    const float* __restrict__ x, const float* __restrict__ gw,
    const __bf16* __restrict__ A2, __bf16* __restrict__ Abuf) {
  __shared__ __align__(16) __bf16 xs[16][2056];  // 64.25 KB, +8 pad
  __shared__ float red[4][16][8];
  __shared__ float cws[16][8];
  const int tid = threadIdx.x;
  const int wave = tid >> 6, lane = tid & 63;
  const int t0 = blockIdx.x * 16;

  // ---- phase 1: one token-row per iteration, fully coalesced ----
#pragma unroll 4
  for (int i = 0; i < 16; ++i) {
    const float* xr = x + (size_t)(t0 + i) * 2048 + tid * 8;
    float4 a = *(const float4*)xr;
    float4 b = *(const float4*)(xr + 4);
    bf16x8 v;
    v[0] = f2bf(a.x); v[1] = f2bf(a.y); v[2] = f2bf(a.z); v[3] = f2bf(a.w);
    v[4] = f2bf(b.x); v[5] = f2bf(b.y); v[6] = f2bf(b.z); v[7] = f2bf(b.w);
    *(bf16x8*)(Abuf + (size_t)(t0 + i) * 2176 + tid * 8) = v;
    *(bf16x8*)&xs[i][tid * 8] = v;
  }
  __syncthreads();

  // ---- phase 2: logits from bf16 x (error ~1e-3 of logit scale; top-2 stable) ----
  const int tok = tid & 15, slc = tid >> 4;
  const int c0 = slc * 128;
  float acc[8] = {0, 0, 0, 0, 0, 0, 0, 0};
  for (int j8 = 0; j8 < 16; ++j8) {
    bf16x8 xv = *(const bf16x8*)&xs[tok][c0 + j8 * 8];
    float xf[8];
#pragma unroll
    for (int j = 0; j < 8; ++j) xf[j] = (float)xv[j];
#pragma unroll
    for (int e = 0; e < 8; ++e) {
      float4 g0 = *(const float4*)(gw + e * 2048 + c0 + j8 * 8);
      float4 g1 = *(const float4*)(gw + e * 2048 + c0 + j8 * 8 + 4);
      acc[e] += xf[0] * g0.x + xf[1] * g0.y + xf[2] * g0.z + xf[3] * g0.w +
                xf[4] * g1.x + xf[5] * g1.y + xf[6] * g1.z + xf[7] * g1.w;
    }
  }
#pragma unroll
  for (int e = 0; e < 8; ++e) {
    acc[e] += __shfl_down(acc[e], 16);
    acc[e] += __shfl_down(acc[e], 32);
  }
  if (lane < 16) {
#pragma unroll
    for (int e = 0; e < 8; ++e) red[wave][lane][e] = acc[e];
  }
  __syncthreads();
  if (tid < 16) {
    float lg[8];
#pragma unroll
    for (int e = 0; e < 8; ++e)
      lg[e] = red[0][tid][e] + red[1][tid][e] + red[2][tid][e] + red[3][tid][e];
    int a = 0;
    for (int e = 1; e < 8; ++e) if (lg[e] > lg[a]) a = e;
    int b = (a == 0) ? 1 : 0;
    for (int e = 0; e < 8; ++e) if (e != a && lg[e] > lg[b]) b = e;
    const float d = __expf(lg[b] - lg[a]);
    float o[8] = {0, 0, 0, 0, 0, 0, 0, 0};
    o[a] = 1.0f / (1.0f + d);
    o[b] = d / (1.0f + d);
#pragma unroll
    for (int e = 0; e < 8; ++e) cws[tid][e] = o[e];
  }
  __syncthreads();

  // ---- phase 3: t = xs @ A2^T, wave handles experts nt0, nt0+1 ----
  const int m = lane & 15, q = lane >> 4;
  const int nt0 = wave * 2;
  f32x4 tacc[2] = {};
  for (int ks = 0; ks < 64; ++ks) {
    bf16x8 af = *(const bf16x8*)&xs[m][ks * 32 + q * 8];
#pragma unroll
    for (int h = 0; h < 2; ++h) {
      bf16x8 bfg = *(const bf16x8*)(A2 + (size_t)((nt0 + h) * 16 + m) * 2048 +
                                    ks * 32 + q * 8);
      tacc[h] = __builtin_amdgcn_mfma_f32_16x16x32_bf16(af, bfg, tacc[h], 0, 0, 0);
    }
  }
  // ---- phase 4: scale + store. C layout: col=lane&15, row=q*4+reg ----
#pragma unroll
  for (int h = 0; h < 2; ++h) {
    const int nt = nt0 + h;
#pragma unroll
    for (int rg = 0; rg < 4; ++rg) {
      const int trow = q * 4 + rg;
      const float s = tacc[h][rg] * 16.0f * cws[trow][nt];
      Abuf[(size_t)(t0 + trow) * 2176 + 2048 + nt * 16 + m] = f2bf(s);
    }
  }
}

// ---------------- MFMA GEMM: C[m,n] = sum_k A[m,k]*B[n,k] (both K-major) ----------------
// 128x64 tile, BK=64, 128 threads (2 waves, each 64x64). Grid 32x32 = 1024 blocks
// -> 4 blocks/CU (4 independent barrier groups). XOR k-chunk swizzle as R1.
__global__ __launch_bounds__(128, 2) void mfma_gemm_bt(
    const __bf16* __restrict__ A, const __bf16* __restrict__ B,
    float* __restrict__ C, int lda, int ldb, int ldc, int kiters) {
  __shared__ __align__(16) __bf16 As[128 * 64];
  __shared__ __align__(16) __bf16 Bs[64 * 64];
  const int tid = threadIdx.x;
  const int wave = tid >> 6;
  const int lane = tid & 63;
  const int tm = blockIdx.x * 128;
  const int tn = blockIdx.y * 64;

  const int wm = wave * 64;
  const int srow = lane >> 3;                 // row within 8-row staging chunk
  const int skoff = ((lane & 7) ^ srow) * 8;  // XOR-swizzled k offset (elems)

  const int rlo = lane & 7;
  const int rb3 = (lane >> 3) & 1;
  const int qb = lane >> 4;

  f32x4 acc[4][4] = {};

  int kcur = 0;
  for (int kt = 0; kt < kiters; ++kt) {
#pragma unroll
    for (int r = 0; r < 8; ++r) {
      const int ch = r * 2 + wave;  // A: 16 chunks of 8 rows
      ld_lds16(A + (size_t)(tm + ch * 8 + srow) * lda + kcur + skoff, &As[ch * 512]);
    }
#pragma unroll
    for (int r = 0; r < 4; ++r) {
      const int ch = r * 2 + wave;  // B: 8 chunks of 8 rows
      ld_lds16(B + (size_t)(tn + ch * 8 + srow) * ldb + kcur + skoff, &Bs[ch * 512]);
    }
    __syncthreads();
#pragma unroll
    for (int ks = 0; ks < 2; ++ks) {
      bf16x8 af[4], bfg[4];
      const int q8 = ((ks * 4 + qb) ^ rlo) * 8;
#pragma unroll
      for (int i = 0; i < 4; ++i) {
        const int rh = ((wm + i * 16) >> 3) + rb3;
        af[i] = *(const bf16x8*)&As[rh * 512 + rlo * 64 + q8];
      }
#pragma unroll
      for (int j = 0; j < 4; ++j) {
        const int rh = ((j * 16) >> 3) + rb3;
        bfg[j] = *(const bf16x8*)&Bs[rh * 512 + rlo * 64 + q8];
      }
#pragma unroll
      for (int i = 0; i < 4; ++i)
#pragma unroll
        for (int j = 0; j < 4; ++j)
          acc[i][j] = __builtin_amdgcn_mfma_f32_16x16x32_bf16(af[i], bfg[j], acc[i][j], 0, 0, 0);
    }
    __syncthreads();
    kcur += 64;
  }

  // C/D layout: col = lane&15, row = (lane>>4)*4 + reg
  const int crow0 = tm + wm + (lane >> 4) * 4;
  const int ccol0 = tn + (lane & 15);
#pragma unroll
  for (int i = 0; i < 4; ++i)
#pragma unroll
    for (int j = 0; j < 4; ++j)
#pragma unroll
      for (int rg = 0; rg < 4; ++rg)
        C[(size_t)(crow0 + i * 16 + rg) * ldc + ccol0 + j * 16] = acc[i][j][rg];
}

extern "C" void kernel_launch(void* const* d_in, const int* in_sizes, int n_in,
                              void* d_out, int out_size, void* d_ws, size_t ws_size,
                              hipStream_t stream) {
  const float* x = (const float*)d_in[0];       // [2,2048,2048] -> [4096,2048]
  const float* weight = (const float*)d_in[1];  // [2048,2048]
  const float* gate_w = (const float*)d_in[2];  // [8,2048]
  const float* A_w = (const float*)d_in[3];     // [8,16,2048] == [128,2048]
  const float* B_w = (const float*)d_in[4];     // [8,2048,16]
  float* out = (float*)d_out;                   // [4096,2048]

  char* ws = (char*)d_ws;
  __bf16* Abuf = (__bf16*)ws;                // [4096,2176] bf16 = 17,825,792 B
  __bf16* Bfull = (__bf16*)(ws + 17825792);  // [2048,2176] bf16 =  8,912,896 B
  __bf16* A2 = (__bf16*)(ws + 26738688);     // [128,2048]  bf16 =    524,288 B

  // 1. prep: W -> Bfull[:,0:2048]; A_w -> A2; B_w -> Bfull[:,2048:2176]
  prep_kernel<<<2240, 256, 0, stream>>>(weight, A_w, B_w, Bfull, A2);
  // 2. router + x->bf16 + LoRA-down (t2) into Abuf
  router_t2<<<256, 256, 0, stream>>>(x, gate_w, A2, Abuf);
  // 3. out = Abuf @ Bfull^T  (K=2176 fuses base + LoRA-up)
  mfma_gemm_bt<<<dim3(32, 32), 128, 0, stream>>>(Abuf, Bfull, out, 2176, 2176,
                                                 2048, 34);
}